// Round 14
// baseline (758.054 us; speedup 1.0000x reference)
//
#include <hip/hip_runtime.h>
#include <hip/hip_bf16.h>

// B=32, T=2048, D=256, H=256, CS=32, N=8, G=4H+2N=1040.
// Scan over BATCH axis (32 steps), carry (T,H). Backward dir = col-reversed W_ih.
#define B_  32
#define T_  2048
#define D_  256
#define H_  256
#define G_  1040

#define NSL 8      // e-slices of width 32 (== CS; slice s == chunk n)
#define NRB 16     // row-blocks of 128 rows
#define NMB 4      // mblocks (1 per wave) of 32 rows
#define NKB 32     // K16 chunks over KK=512
#define NF  5      // B col-frags: og,cg,ig,fg (32 cols) + [cols 0..15 | zeros]
#define CTRSTRIDE 64   // ints per group counter slot (256 B)

#define NBWSW 640    // build_wsw blocks (163840/256)

using bf16   = __hip_bfloat16;
using short8 = __attribute__((ext_vector_type(8))) short;
using f32x16 = __attribute__((ext_vector_type(16))) float;
using ull    = unsigned long long;

__device__ inline float sigmoidf_(float v) {
  return __fdividef(1.f, 1.f + __expf(-v));
}
__device__ inline float tanh_(float v) {
  v = fminf(fmaxf(v, -15.f), 15.f);
  float e = __expf(2.f * v);
  return __fdividef(e - 1.f, e + 1.f);
}
__device__ inline float bf2f(unsigned short u) {
  union { unsigned int i; float f; } c; c.i = ((unsigned int)u) << 16; return c.f;
}
__device__ inline float ldF(const void* p, size_t i, int isf) {
  return isf ? ((const float*)p)[i] : bf2f(((const unsigned short*)p)[i]);
}
__device__ inline short f2bs(float v) {
  bf16 h = __float2bfloat16(v);
  return *(short*)&h;
}

// ---------------------------------------------------------------------------
// Fused prep (round-14: xs build DELETED — persist loads A-frags directly
// from x). One dispatch: every block recomputes the fp32-detection inline;
// block 0 writes meta + bsum; blocks [1,641) build the Wsw B-frag image.
// ---------------------------------------------------------------------------
__global__ __launch_bounds__(256) void prep_all(
    const void* __restrict__ x, const int* __restrict__ sli,
    const void* __restrict__ W_ih, const void* __restrict__ b_ih,
    const void* __restrict__ W_hh, const void* __restrict__ b_hh,
    int* __restrict__ meta, float* __restrict__ bsum,
    bf16* __restrict__ Wsw)
{
  const int tid = threadIdx.x;

  // ---- inline fp32 detection ----
  __shared__ int s_bad;
  if (tid == 0) s_bad = 0;
  __syncthreads();
  {
    const unsigned short* xh = (const unsigned short*)x;
    int bad = 0;
    #pragma unroll
    for (int j = 0; j < 4; ++j) {
      float f = bf2f(xh[tid * 4 + j]);
      if (!(fabsf(f) < 100.f)) bad = 1;
    }
    if (bad) atomicOr(&s_bad, 1);
  }
  __syncthreads();
  const int isf = s_bad;

  const int blk = blockIdx.x;

  if (blk == 0) {
    // meta: [0]=is_fp32, [8+b]=seq_len[b], [40+b]=row base[b]
    if (tid == 0) {
      meta[0] = isf;
      bool is64 = true;
      for (int i = 1; i < 32; i += 2) if (sli[i] != 0) is64 = false;
      int base = 0;
      for (int b = 0; b < B_; ++b) {
        int v = is64 ? sli[2 * b] : sli[b];
        meta[8 + b]  = v;
        meta[40 + b] = base;
        base += v;
      }
    }
    for (int i = tid; i < G_; i += 256)
      bsum[i] = ldF(b_ih, i, isf) + ldF(b_hh, i, isf);
    return;
  }

  // Wsw[d][s][kb(32)][f(5)][lane(64)][8]: B-frag image.
  {
    const int idx = (blk - 1) * 256 + tid;   // over 163840
    const int lane = idx & 63;
    const int f    = (idx >> 6) % NF;
    const int kb   = (idx / (64 * NF)) % NKB;
    const int sl   = (idx / (64 * NF * NKB)) % NSL;
    const int d    = idx / (64 * NF * NKB * NSL);
    const int n    = lane & 31;
    const int k0   = kb * 16 + (lane >> 5) * 8;
    const int g = (f < 4) ? (16 + f * H_ + sl * 32 + n) : ((n < 16) ? n : -1);
    short8 v;
    #pragma unroll
    for (int j = 0; j < 8; ++j) {
      float val = 0.f;
      const int k = k0 + j;
      if (g >= 0)
        val = (k < D_) ? ldF(W_ih, (size_t)g * D_ + (d ? (D_ - 1 - k) : k), isf)
                       : ldF(W_hh, (size_t)g * H_ + (k - D_), isf);
      v[j] = f2bs(val);
    }
    *(short8*)(Wsw + (size_t)idx * 8) = v;
  }
}

// ---------------------------------------------------------------------------
// Persistent fused recurrence. Round-14 = round-13 (passing) with the A-frag
// source changed from the xs intermediate buffer to DIRECT x loads:
//  - A-frag layout is definitionally lane l -> x[(b*T + rb*128+w*32+(l&31))*D
//    + kb*16 + (l>>5)*8 ..+8], so a per-lane strided load from x IS the frag.
//  - loads sit in the existing cross-step prefetch slots (~12us of slack
//    under poll+hs+epilogue); x is L3-resident and XCD-L2-shared by the 16
//    sibling blocks per rb. fp32 input adds 8 cvts/chunk (same conversion
//    build_xs did, now hidden under stall).
//  - deletes the 32MB xs buffer, its 8192-block build (~65us), and the 4MB
//    hs memset (dead: step 0 writes parity 0 before step 1 reads it).
//  Sync structure / GEMMs / epilogue byte-identical to R13.
// ---------------------------------------------------------------------------
__global__ __launch_bounds__(256, 1) void onlstm_persist(
    const void* __restrict__ x, const short* __restrict__ Wsw,
    short* __restrict__ hs, float* __restrict__ cs,
    const float* __restrict__ bsum, void* __restrict__ out,
    const int* __restrict__ meta, int* __restrict__ ctr,
    int b_lo, int b_hi)
{
  __shared__ short Wl[NKB * 4 * 512];          // 128 KiB: frags f0..3
  __shared__ __align__(16) short Ht[NMB][32][40];  // 10 KiB: per-wave hy transpose

  const int tid  = threadIdx.x;
  const int lane = tid & 63;
  const int w    = tid >> 6;            // wave = mblock

  // XCD-grouped: group (rb,d) siblings (s=0..7) share lin%8 -> same XCD.
  const int lin = blockIdx.x;
  const int rb  = (lin & 7) + 8 * ((lin >> 3) >> 4);
  const int p   = (lin >> 3) & 15;
  const int d   = p >> 3;
  const int s   = p & 7;

  const int col   = lane & 31;
  const int khalf = lane >> 5;
  const int isf   = meta[0];

  const short* wsrc = Wsw + ((size_t)(d * NSL + s) * NKB) * (NF * 512);

  // ---- one-time: stage f0..3 frags into LDS (coalesced 16B/lane) ----
  for (int i = tid; i < NKB * 4 * 64; i += 256) {
    const int kb = i >> 8, rem = i & 255, f = rem >> 6, l = rem & 63;
    *(short8*)&Wl[((kb * 4 + f) << 9) + (l << 3)] =
        *(const short8*)(wsrc + ((kb * 5 + f) << 9) + (l << 3));
  }
  __syncthreads();

  // bias preloads (L1/L2 hits)
  float bg[4];
  #pragma unroll
  for (int f = 0; f < 4; ++f) bg[f] = bsum[16 + f * H_ + s * 32 + col];
  const float c0b = (col < 16) ? bsum[col] : 0.f;

  // epilogue addressing for e = s*32+col
  const int e = s * 32 + col;

  int* gctr = ctr + (size_t)(d * NRB + rb) * CTRSTRIDE;  // private cacheline
  const short* w4p = wsrc + 4 * 512 + lane * 8;   // f4 frag, stride 5*512/chunk

  float* csP = cs + (((size_t)(d * NSL + s) * NRB + rb) * NMB + w) * 1024 + lane;

  // per-lane A-frag source offset within one batch-slab of x:
  // element (t, k) with t = rb*128 + w*32 + (lane&31), k = kb*16 + (lane>>5)*8
  const size_t rowoff = ((size_t)(rb * 128 + w * 32 + (lane & 31))) * D_
                        + (lane >> 5) * 8;

  // direct A-frag load from x (bf16: 16B copy; fp32: 2x16B + 8 cvt)
  auto loadA = [&](size_t elemoff) -> short8 {
    if (!isf) return *(const short8*)((const unsigned short*)x + elemoff);
    const float* xf = (const float*)x + elemoff;
    short8 v;
    #pragma unroll
    for (int j = 0; j < 8; ++j) v[j] = f2bs(xf[j]);
    return v;
  };

  f32x16 creg;                                    // c carry: registers
  if (b_lo > 0) {
    #pragma unroll
    for (int r = 0; r < 16; ++r) creg[r] = csP[r * 64];
  } else {
    #pragma unroll
    for (int r = 0; r < 16; ++r) creg[r] = 0.f;
  }

  // prologue: synchronously prefetch step b_lo's A-chunks into registers
  short8 xn[16];
  {
    const size_t base0 = (size_t)b_lo * T_ * D_ + rowoff;
    #pragma unroll
    for (int kb = 0; kb < 16; ++kb)
      xn[kb] = loadA(base0 + (size_t)kb * 16);
  }

  for (int b = b_lo; b < b_hi; ++b) {
    const int len_s  = meta[8 + b];
    const int base_s = meta[40 + b];
    const bool lastb = (b + 1 >= B_);

    f32x16 acc[NF];
    #pragma unroll
    for (int f = 0; f < NF; ++f)
      #pragma unroll
      for (int r = 0; r < 16; ++r) acc[f][r] = 0.f;

    // ---- xs half (K chunks 0..15): A from registers (cross-step prefetch
    // DIRECT from x into the same regs); Wl frags double-buffered in regs
    // (kb+1's ds_reads issued before kb's MFMAs); f4 pipelined 3-deep. ----
    {
      const size_t baseN = (size_t)(b + 1) * T_ * D_ + rowoff;
      const bool pf = (b + 1 < b_hi);
      const short* w4q = w4p;
      short8 q0 = *(const short8*)(w4q);
      short8 q1 = *(const short8*)(w4q + 2560);
      short8 q2 = *(const short8*)(w4q + 5120);
      short8 wf[2][4];
      #pragma unroll
      for (int f = 0; f < 4; ++f)
        wf[0][f] = *(const short8*)&Wl[((0 * 4 + f) << 9) + (lane << 3)];
      #pragma unroll
      for (int kb = 0; kb < 16; ++kb) {
        const int cur = kb & 1;            // static after full unroll
        if (kb + 1 < 16) {
          #pragma unroll
          for (int f = 0; f < 4; ++f)
            wf[cur ^ 1][f] = *(const short8*)&Wl[(((kb + 1) * 4 + f) << 9) + (lane << 3)];
        }
        const short8 af = xn[kb];
        if (pf) xn[kb] = loadA(baseN + (size_t)kb * 16);   // next-step prefetch
        const short8 b4 = q0;
        q0 = q1; q1 = q2;
        if (kb < 13) q2 = *(const short8*)(w4q + (kb + 3) * 2560);
        #pragma unroll
        for (int f = 0; f < 4; ++f)
          acc[f] = __builtin_amdgcn_mfma_f32_32x32x16_bf16(af, wf[cur][f], acc[f], 0, 0, 0);
        acc[4] = __builtin_amdgcn_mfma_f32_32x32x16_bf16(af, b4, acc[4], 0, 0, 0);
      }
    }

    // ---- wait: tid0 polls (8 sibling blocks signaled step b-1), then
    // __syncthreads releases the block (proven read side). ----
    if (b) {
      if (tid == 0) {
        ull t0 = __builtin_amdgcn_s_memrealtime();
        while (__hip_atomic_load(gctr, __ATOMIC_RELAXED,
                                 __HIP_MEMORY_SCOPE_AGENT) < 8 * b) {
          __builtin_amdgcn_s_sleep(1);
          if (__builtin_amdgcn_s_memrealtime() - t0 > 40000000ull) break; // no hang
        }
      }
      __syncthreads();

      // prefetch all 16 h-chunks (parity (b&1)^1) via coherent 8B atomic loads
      ull hfA[16], hfB[16];
      {
        const short* hbase = hs + (((size_t)(((b & 1) ^ 1) * 2 + d) * NRB + rb) * 16 * NMB + w) * 512;
        #pragma unroll
        for (int kb = 0; kb < 16; ++kb) {
          const ull* hp = (const ull*)(hbase + (size_t)kb * NMB * 512) + lane * 2;
          hfA[kb] = __hip_atomic_load(hp,     __ATOMIC_RELAXED, __HIP_MEMORY_SCOPE_AGENT);
          hfB[kb] = __hip_atomic_load(hp + 1, __ATOMIC_RELAXED, __HIP_MEMORY_SCOPE_AGENT);
        }
      }

      // hs half (K chunks 16..31): A from prefetched regs, Wl frags
      // double-buffered, f4 pipelined.
      const short* w4q = w4p + 16 * 2560;
      short8 q0 = *(const short8*)(w4q);
      short8 q1 = *(const short8*)(w4q + 2560);
      short8 q2 = *(const short8*)(w4q + 5120);
      short8 wf[2][4];
      #pragma unroll
      for (int f = 0; f < 4; ++f)
        wf[0][f] = *(const short8*)&Wl[(((16 * 4) + f) << 9) + (lane << 3)];
      #pragma unroll
      for (int kb = 0; kb < 16; ++kb) {
        const int cur = kb & 1;
        if (kb + 1 < 16) {
          #pragma unroll
          for (int f = 0; f < 4; ++f)
            wf[cur ^ 1][f] = *(const short8*)&Wl[(((16 + kb + 1) * 4 + f) << 9) + (lane << 3)];
        }
        union { ull u[2]; short8 v; } af;
        af.u[0] = hfA[kb]; af.u[1] = hfB[kb];
        const short8 b4 = q0;
        q0 = q1; q1 = q2;
        if (kb < 13) q2 = *(const short8*)(w4q + (kb + 3) * 2560);
        #pragma unroll
        for (int f = 0; f < 4; ++f)
          acc[f] = __builtin_amdgcn_mfma_f32_32x32x16_bf16(af.v, wf[cur][f], acc[f], 0, 0, 0);
        acc[4] = __builtin_amdgcn_mfma_f32_32x32x16_bf16(af.v, b4, acc[4], 0, 0, 0);
      }
    }
    // b==0: h is zero, hs half contributes nothing -> skipped entirely.

    // ---- epilogue ----
    // C layout: col = lane&31, row = (r&3) + 8*(r>>2) + 4*(lane>>5).
    // Stage-batched shuffle trees (16 parallel chains).
    f32x16 gv, mx, Sv, Pv;
    #pragma unroll
    for (int r = 0; r < 16; ++r) gv[r] = acc[4][r] + c0b;  // cols>=16: exactly 0
    #pragma unroll
    for (int r = 0; r < 16; ++r) mx[r] = gv[r];
    #pragma unroll
    for (int r = 0; r < 16; ++r) { float t = __shfl_xor(mx[r], 1); mx[r] = fmaxf(mx[r], t); }
    #pragma unroll
    for (int r = 0; r < 16; ++r) { float t = __shfl_xor(mx[r], 2); mx[r] = fmaxf(mx[r], t); }
    #pragma unroll
    for (int r = 0; r < 16; ++r) { float t = __shfl_xor(mx[r], 4); mx[r] = fmaxf(mx[r], t); }
    #pragma unroll
    for (int r = 0; r < 16; ++r) gv[r] = __expf(gv[r] - mx[r]);   // gv := ex
    const bool pin = (lane & 7) <= s;
    #pragma unroll
    for (int r = 0; r < 16; ++r) { Sv[r] = gv[r]; Pv[r] = pin ? gv[r] : 0.f; }
    #pragma unroll
    for (int r = 0; r < 16; ++r) { Sv[r] += __shfl_xor(Sv[r], 1); Pv[r] += __shfl_xor(Pv[r], 1); }
    #pragma unroll
    for (int r = 0; r < 16; ++r) { Sv[r] += __shfl_xor(Sv[r], 2); Pv[r] += __shfl_xor(Pv[r], 2); }
    #pragma unroll
    for (int r = 0; r < 16; ++r) { Sv[r] += __shfl_xor(Sv[r], 4); Pv[r] += __shfl_xor(Pv[r], 4); }
    #pragma unroll
    for (int r = 0; r < 16; ++r) Pv[r] = __fdividef(Pv[r], Sv[r]);  // Pv := ratio
    f32x16 cinv, cfgv;
    #pragma unroll
    for (int r = 0; r < 16; ++r) cinv[r] = 1.f - __shfl(Pv[r], khalf * 32);
    #pragma unroll
    for (int r = 0; r < 16; ++r) cfgv[r] = __shfl(Pv[r], khalf * 32 + 8);

    #pragma unroll
    for (int r = 0; r < 16; ++r) {
      const int row = (r & 3) + 8 * (r >> 2) + 4 * khalf;
      const float cin = cinv[r];
      const float cfg = cfgv[r];
      const float og = sigmoidf_(acc[0][r] + bg[0]);
      const float cg = tanh_   (acc[1][r] + bg[1]);
      const float ig = sigmoidf_(acc[2][r] + bg[2]);
      const float fg = sigmoidf_(acc[3][r] + bg[3]);
      const float ov = cfg * cin;
      const float f2 = fg * ov + (cfg - ov);
      const float i2 = ig * ov + (cin - ov);
      const float cy = f2 * creg[r] + i2 * cg;
      creg[r] = cy;
      const float hy = og * tanh_(cy);
      if (!lastb) Ht[w][row][col] = f2bs(hy);   // wave-private transpose tile
      const int t = rb * 128 + w * 32 + row;
      if (t < len_s) {
        const size_t o = (size_t)(base_s + t) * (2 * H_) + (size_t)d * H_ + e;
        if (isf) ((float*)out)[o] = hy;
        else     ((bf16*)out)[o]  = __float2bfloat16(hy);
      }
    }

    // ---- hy -> A-frag image via coherent 8B atomic stores (4/lane);
    // skipped on the last step (never read). ----
    if (!lastb) {
      const int m  = lane & 31;
      const int k8 = lane >> 5;
      short* hbase = hs + (((size_t)((b & 1) * 2 + d) * NRB + rb) * 16 * NMB + w) * 512;
      #pragma unroll
      for (int c = 0; c < 2; ++c) {
        ull lo = *(const ull*)&Ht[w][m][c * 16 + k8 * 8];
        ull hi = *(const ull*)&Ht[w][m][c * 16 + k8 * 8 + 4];
        ull* q = (ull*)(hbase + (size_t)(2 * s + c) * NMB * 512) + lane * 2;
        __hip_atomic_store(q,     lo, __ATOMIC_RELAXED, __HIP_MEMORY_SCOPE_AGENT);
        __hip_atomic_store(q + 1, hi, __ATOMIC_RELAXED, __HIP_MEMORY_SCOPE_AGENT);
      }
    }

    // ---- arrive: barrier drains all stores (vmcnt(0) before s_barrier),
    // then one RELAXED add signals (proven write side). ----
    __syncthreads();
    if (tid == 0)
      __hip_atomic_fetch_add(gctr, 1, __ATOMIC_RELAXED, __HIP_MEMORY_SCOPE_AGENT);
  }

  if (b_hi < B_) {                 // per-step fallback mode: spill c carry
    #pragma unroll
    for (int r = 0; r < 16; ++r) csP[r * 64] = creg[r];
  }
}

// ---------------------------------------------------------------------------
extern "C" void kernel_launch(void* const* d_in, const int* in_sizes, int n_in,
                              void* d_out, int out_size, void* d_ws, size_t ws_size,
                              hipStream_t stream)
{
  const void* x    = d_in[0];
  const int*  sl   = (const int*)d_in[1];
  const void* W_ih = d_in[2];
  const void* b_ih = d_in[3];
  const void* W_hh = d_in[4];
  const void* b_hh = d_in[5];

  char* ws = (char*)d_ws;
  size_t off = 0;
  auto alloc = [&](size_t bytes) {
    void* p = ws + off;
    off = (off + bytes + 255) & ~(size_t)255;
    return p;
  };
  int*   meta = (int*)  alloc(128 * sizeof(int));
  short* Wsw  = (short*)alloc((size_t)2 * NSL * NKB * NF * 512 * sizeof(short)); // 2.6 MB
  short* hs   = (short*)alloc((size_t)2 * 2 * T_ * H_ * sizeof(short));         // 4 MB [parity][dir]
  float* bsum = (float*)alloc((size_t)G_ * sizeof(float));
  int*   ctr  = (int*)  alloc((size_t)32 * CTRSTRIDE * sizeof(int));            // padded: 1 line/group
  float* cs   = (float*)alloc((size_t)2 * NSL * NRB * NMB * 1024 * sizeof(float)); // 4 MB (fallback only)
  const bool have_cs = (off <= ws_size);

  // hs memset DELETED (dead: step 0 writes parity 0 before step 1 reads it).
  hipMemsetAsync(ctr, 0, (size_t)32 * CTRSTRIDE * sizeof(int), stream);

  // ONE prep dispatch: meta + bsum + Wsw (xs build deleted).
  prep_all<<<1 + NBWSW, 256, 0, stream>>>(
      x, sl, W_ih, b_ih, W_hh, b_hh, meta, bsum, (bf16*)Wsw);

  // Preferred: cooperative persistent launch (co-residency guaranteed).
  int b_lo = 0, b_hi = B_;
  void* args[] = {(void*)&x, (void*)&Wsw, (void*)&hs, (void*)&cs, (void*)&bsum,
                  (void*)&d_out, (void*)&meta, (void*)&ctr, (void*)&b_lo, (void*)&b_hi};
  hipError_t ce = hipLaunchCooperativeKernel((const void*)onlstm_persist,
                                             dim3(256), dim3(256), args, 0, stream);
  if (ce != hipSuccess) {
    (void)hipGetLastError();   // clear error state
    if (have_cs) {
      // Fallback: per-step launches; inter-step sync = kernel boundary.
      // Counter accumulates 8/group/launch, matching the 8*b thresholds.
      for (int b = 0; b < B_; ++b)
        onlstm_persist<<<dim3(256), dim3(256), 0, stream>>>(
            x, Wsw, hs, cs, bsum, d_out, meta, ctr, b, b + 1);
    } else {
      // Last resort: regular persistent launch (structural residency + timeout).
      onlstm_persist<<<dim3(256), dim3(256), 0, stream>>>(
          x, Wsw, hs, cs, bsum, d_out, meta, ctr, 0, B_);
    }
  }
}

// Round 15
// 611.629 us; speedup vs baseline: 1.2394x; 1.2394x over previous
//
#include <hip/hip_runtime.h>
#include <hip/hip_bf16.h>

// B=32, T=2048, D=256, H=256, CS=32, N=8, G=4H+2N=1040.
// Scan over BATCH axis (32 steps), carry (T,H). Backward dir = col-reversed W_ih.
#define B_  32
#define T_  2048
#define D_  256
#define H_  256
#define G_  1040

#define NSL 8      // e-slices of width 32 (== CS; slice s == chunk n)
#define NRB 16     // row-blocks of 128 rows
#define NMB 4      // mblocks (1 per wave) of 32 rows
#define NKB 32     // K16 chunks over KK=512
#define NF  5      // B col-frags: og,cg,ig,fg (32 cols) + [cols 0..15 | zeros]
#define CTRSTRIDE 64   // ints per group counter slot (256 B)

#define NBXT  512    // tiled xs blocks (B*NRB)
#define NBWSW 640    // Wsw blocks (163840/256)
#define XLP   264    // LDS x-tile row stride in elems (528 B: 16B-aligned)

using bf16   = __hip_bfloat16;
using short8 = __attribute__((ext_vector_type(8))) short;
using f32x16 = __attribute__((ext_vector_type(16))) float;
using ull    = unsigned long long;

__device__ inline float sigmoidf_(float v) {
  return __fdividef(1.f, 1.f + __expf(-v));
}
__device__ inline float tanh_(float v) {
  v = fminf(fmaxf(v, -15.f), 15.f);
  float e = __expf(2.f * v);
  return __fdividef(e - 1.f, e + 1.f);
}
__device__ inline float bf2f(unsigned short u) {
  union { unsigned int i; float f; } c; c.i = ((unsigned int)u) << 16; return c.f;
}
__device__ inline float ldF(const void* p, size_t i, int isf) {
  return isf ? ((const float*)p)[i] : bf2f(((const unsigned short*)p)[i]);
}
__device__ inline short f2bs(float v) {
  bf16 h = __float2bfloat16(v);
  return *(short*)&h;
}

// ---------------------------------------------------------------------------
// Fused prep, round-15: xs build is back (R14's direct-x loads were 512B-
// strided = uncoalesced, persist 488->677) but now BOTH-SIDES-COALESCED via
// an LDS-tiled transpose: one block per (b,rb) loads the 128x256 x tile
// row-linearly (64KB LDS, stride 264 elems = 16B-aligned rows), then writes
// the A-frag image in output-linear order (waves write contiguous 1KB runs).
// Old build: coalesced loads + scattered 16B writes = 1.5 TB/s (~65us).
// Block 0: meta+bsum. Blocks [1,513): xs tiles. Blocks [513,1153): Wsw.
// ---------------------------------------------------------------------------
__global__ __launch_bounds__(256) void prep_all(
    const void* __restrict__ x, const int* __restrict__ sli,
    const void* __restrict__ W_ih, const void* __restrict__ b_ih,
    const void* __restrict__ W_hh, const void* __restrict__ b_hh,
    int* __restrict__ meta, float* __restrict__ bsum,
    bf16* __restrict__ xs, bf16* __restrict__ Wsw)
{
  __shared__ __align__(16) short xt[128 * XLP];   // 66 KB x tile
  const int tid = threadIdx.x;

  // ---- inline fp32 detection (all blocks; 2KB, L2-broadcast) ----
  __shared__ int s_bad;
  if (tid == 0) s_bad = 0;
  __syncthreads();
  {
    const unsigned short* xh = (const unsigned short*)x;
    int bad = 0;
    #pragma unroll
    for (int j = 0; j < 4; ++j) {
      float f = bf2f(xh[tid * 4 + j]);
      if (!(fabsf(f) < 100.f)) bad = 1;
    }
    if (bad) atomicOr(&s_bad, 1);
  }
  __syncthreads();
  const int isf = s_bad;

  const int blk = blockIdx.x;

  if (blk == 0) {
    // meta: [0]=is_fp32, [8+b]=seq_len[b], [40+b]=row base[b]
    if (tid == 0) {
      meta[0] = isf;
      bool is64 = true;
      for (int i = 1; i < 32; i += 2) if (sli[i] != 0) is64 = false;
      int base = 0;
      for (int b = 0; b < B_; ++b) {
        int v = is64 ? sli[2 * b] : sli[b];
        meta[8 + b]  = v;
        meta[40 + b] = base;
        base += v;
      }
    }
    for (int i = tid; i < G_; i += 256)
      bsum[i] = ldF(b_ih, i, isf) + ldF(b_hh, i, isf);
    return;
  }

  if (blk < 1 + NBXT) {
    // ---- tiled xs build for (b, rb) ----
    const int bi = blk - 1;
    const int b  = bi >> 4;
    const int rb = bi & 15;
    const unsigned short* xh = (const unsigned short*)x;
    const float* xf = (const float*)x;

    // load phase: rows linear, fully coalesced (wave = 2 rows x 512B)
    #pragma unroll
    for (int i = 0; i < 16; ++i) {
      const int li  = i * 256 + tid;        // 8-elem chunk id, 0..4095
      const int tr  = li >> 5;              // 0..127
      const int col = (li & 31) * 8;        // 0..248
      const size_t src = ((size_t)b * T_ + rb * 128 + tr) * D_ + col;
      short8 v;
      if (!isf) {
        v = *(const short8*)(xh + src);
      } else {
        #pragma unroll
        for (int j = 0; j < 8; ++j) v[j] = f2bs(xf[src + j]);
      }
      *(short8*)&xt[tr * XLP + col] = v;
    }
    __syncthreads();

    // store phase: output-linear, fully coalesced (wave writes 1KB runs)
    // out chunk oc = kbx*256 + mb*64 + lane_o; lane_o = k8*32 + trow;
    // source elem = xt[mb*32+trow][kbx*16 + k8*8 ..+8]
    bf16* xsBase = xs + ((size_t)b * 16 + rb) * (16 * 4 * 64 * 8);
    #pragma unroll
    for (int i = 0; i < 16; ++i) {
      const int oc     = i * 256 + tid;     // 0..4095
      const int lane_o = oc & 63;
      const int mb     = (oc >> 6) & 3;
      const int kbx    = oc >> 8;
      const int tr  = mb * 32 + (lane_o & 31);
      const int col = kbx * 16 + (lane_o >> 5) * 8;
      short8 v = *(const short8*)&xt[tr * XLP + col];
      *(short8*)(xsBase + (size_t)oc * 8) = v;
    }
    return;
  }

  // Wsw[d][s][kb(32)][f(5)][lane(64)][8]: B-frag image.
  {
    const int idx = (blk - 1 - NBXT) * 256 + tid;   // over 163840
    const int lane = idx & 63;
    const int f    = (idx >> 6) % NF;
    const int kb   = (idx / (64 * NF)) % NKB;
    const int sl   = (idx / (64 * NF * NKB)) % NSL;
    const int d    = idx / (64 * NF * NKB * NSL);
    const int n    = lane & 31;
    const int k0   = kb * 16 + (lane >> 5) * 8;
    const int g = (f < 4) ? (16 + f * H_ + sl * 32 + n) : ((n < 16) ? n : -1);
    short8 v;
    #pragma unroll
    for (int j = 0; j < 8; ++j) {
      float val = 0.f;
      const int k = k0 + j;
      if (g >= 0)
        val = (k < D_) ? ldF(W_ih, (size_t)g * D_ + (d ? (D_ - 1 - k) : k), isf)
                       : ldF(W_hh, (size_t)g * H_ + (k - D_), isf);
      v[j] = f2bs(val);
    }
    *(short8*)(Wsw + (size_t)idx * 8) = v;
  }
}

// ---------------------------------------------------------------------------
// Persistent fused recurrence. Round-15 = round-13 byte-identical (best
// passing: 488us persist). R14's direct-x A-frag loads reverted (512B-
// strided = 64 cachelines/instruction; persist 488->677, FETCH +16MB).
// hs memset stays deleted (validated R14: step 0 writes parity 0 before
// step 1 reads it; initial hs never read).
// ---------------------------------------------------------------------------
__global__ __launch_bounds__(256, 1) void onlstm_persist(
    const short* __restrict__ xs, const short* __restrict__ Wsw,
    short* __restrict__ hs, float* __restrict__ cs,
    const float* __restrict__ bsum, void* __restrict__ out,
    const int* __restrict__ meta, int* __restrict__ ctr,
    int b_lo, int b_hi)
{
  __shared__ short Wl[NKB * 4 * 512];          // 128 KiB: frags f0..3
  __shared__ __align__(16) short Ht[NMB][32][40];  // 10 KiB: per-wave hy transpose

  const int tid  = threadIdx.x;
  const int lane = tid & 63;
  const int w    = tid >> 6;            // wave = mblock

  // XCD-grouped: group (rb,d) siblings (s=0..7) share lin%8 -> same XCD.
  const int lin = blockIdx.x;
  const int rb  = (lin & 7) + 8 * ((lin >> 3) >> 4);
  const int p   = (lin >> 3) & 15;
  const int d   = p >> 3;
  const int s   = p & 7;

  const int col   = lane & 31;
  const int khalf = lane >> 5;
  const int isf   = meta[0];

  const short* wsrc = Wsw + ((size_t)(d * NSL + s) * NKB) * (NF * 512);

  // ---- one-time: stage f0..3 frags into LDS (coalesced 16B/lane) ----
  for (int i = tid; i < NKB * 4 * 64; i += 256) {
    const int kb = i >> 8, rem = i & 255, f = rem >> 6, l = rem & 63;
    *(short8*)&Wl[((kb * 4 + f) << 9) + (l << 3)] =
        *(const short8*)(wsrc + ((kb * 5 + f) << 9) + (l << 3));
  }
  __syncthreads();

  // bias preloads (L1/L2 hits)
  float bg[4];
  #pragma unroll
  for (int f = 0; f < 4; ++f) bg[f] = bsum[16 + f * H_ + s * 32 + col];
  const float c0b = (col < 16) ? bsum[col] : 0.f;

  // epilogue addressing for e = s*32+col
  const int e = s * 32 + col;

  int* gctr = ctr + (size_t)(d * NRB + rb) * CTRSTRIDE;  // private cacheline
  const short* w4p = wsrc + 4 * 512 + lane * 8;   // f4 frag, stride 5*512/chunk

  float* csP = cs + (((size_t)(d * NSL + s) * NRB + rb) * NMB + w) * 1024 + lane;

  f32x16 creg;                                    // c carry: registers
  if (b_lo > 0) {
    #pragma unroll
    for (int r = 0; r < 16; ++r) creg[r] = csP[r * 64];
  } else {
    #pragma unroll
    for (int r = 0; r < 16; ++r) creg[r] = 0.f;
  }

  // prologue: synchronously prefetch step b_lo's xs chunks into registers
  short8 xn[16];
  {
    const short* aPtr = xs + (((size_t)b_lo * NRB + rb) * 16 * NMB + w) * 512 + lane * 8;
    #pragma unroll
    for (int kb = 0; kb < 16; ++kb)
      xn[kb] = *(const short8*)(aPtr + (size_t)kb * 2048);
  }

  for (int b = b_lo; b < b_hi; ++b) {
    const int len_s  = meta[8 + b];
    const int base_s = meta[40 + b];
    const bool lastb = (b + 1 >= B_);

    f32x16 acc[NF];
    #pragma unroll
    for (int f = 0; f < NF; ++f)
      #pragma unroll
      for (int r = 0; r < 16; ++r) acc[f][r] = 0.f;

    // ---- xs half (K chunks 0..15): A from registers (cross-step prefetch
    // into the same regs); Wl frags DOUBLE-BUFFERED in regs (kb+1's ds_reads
    // issued before kb's MFMAs); f4 pipelined 3-deep from global. ----
    {
      const short* aNext = xs + (((size_t)(b + 1) * NRB + rb) * 16 * NMB + w) * 512 + lane * 8;
      const bool pf = (b + 1 < b_hi);
      const short* w4q = w4p;
      short8 q0 = *(const short8*)(w4q);
      short8 q1 = *(const short8*)(w4q + 2560);
      short8 q2 = *(const short8*)(w4q + 5120);
      short8 wf[2][4];
      #pragma unroll
      for (int f = 0; f < 4; ++f)
        wf[0][f] = *(const short8*)&Wl[((0 * 4 + f) << 9) + (lane << 3)];
      #pragma unroll
      for (int kb = 0; kb < 16; ++kb) {
        const int cur = kb & 1;            // static after full unroll
        if (kb + 1 < 16) {
          #pragma unroll
          for (int f = 0; f < 4; ++f)
            wf[cur ^ 1][f] = *(const short8*)&Wl[(((kb + 1) * 4 + f) << 9) + (lane << 3)];
        }
        const short8 af = xn[kb];
        if (pf) xn[kb] = *(const short8*)(aNext + (size_t)kb * 2048);  // next-step prefetch
        const short8 b4 = q0;
        q0 = q1; q1 = q2;
        if (kb < 13) q2 = *(const short8*)(w4q + (kb + 3) * 2560);
        #pragma unroll
        for (int f = 0; f < 4; ++f)
          acc[f] = __builtin_amdgcn_mfma_f32_32x32x16_bf16(af, wf[cur][f], acc[f], 0, 0, 0);
        acc[4] = __builtin_amdgcn_mfma_f32_32x32x16_bf16(af, b4, acc[4], 0, 0, 0);
      }
    }

    // ---- wait: tid0 polls (8 sibling blocks signaled step b-1), then
    // __syncthreads releases the block (proven read side). ----
    if (b) {
      if (tid == 0) {
        ull t0 = __builtin_amdgcn_s_memrealtime();
        while (__hip_atomic_load(gctr, __ATOMIC_RELAXED,
                                 __HIP_MEMORY_SCOPE_AGENT) < 8 * b) {
          __builtin_amdgcn_s_sleep(1);
          if (__builtin_amdgcn_s_memrealtime() - t0 > 40000000ull) break; // no hang
        }
      }
      __syncthreads();

      // prefetch all 16 h-chunks (parity (b&1)^1) via coherent 8B atomic loads
      ull hfA[16], hfB[16];
      {
        const short* hbase = hs + (((size_t)(((b & 1) ^ 1) * 2 + d) * NRB + rb) * 16 * NMB + w) * 512;
        #pragma unroll
        for (int kb = 0; kb < 16; ++kb) {
          const ull* hp = (const ull*)(hbase + (size_t)kb * NMB * 512) + lane * 2;
          hfA[kb] = __hip_atomic_load(hp,     __ATOMIC_RELAXED, __HIP_MEMORY_SCOPE_AGENT);
          hfB[kb] = __hip_atomic_load(hp + 1, __ATOMIC_RELAXED, __HIP_MEMORY_SCOPE_AGENT);
        }
      }

      // hs half (K chunks 16..31): A from prefetched regs, Wl frags
      // double-buffered, f4 pipelined.
      const short* w4q = w4p + 16 * 2560;
      short8 q0 = *(const short8*)(w4q);
      short8 q1 = *(const short8*)(w4q + 2560);
      short8 q2 = *(const short8*)(w4q + 5120);
      short8 wf[2][4];
      #pragma unroll
      for (int f = 0; f < 4; ++f)
        wf[0][f] = *(const short8*)&Wl[(((16 * 4) + f) << 9) + (lane << 3)];
      #pragma unroll
      for (int kb = 0; kb < 16; ++kb) {
        const int cur = kb & 1;
        if (kb + 1 < 16) {
          #pragma unroll
          for (int f = 0; f < 4; ++f)
            wf[cur ^ 1][f] = *(const short8*)&Wl[(((16 + kb + 1) * 4 + f) << 9) + (lane << 3)];
        }
        union { ull u[2]; short8 v; } af;
        af.u[0] = hfA[kb]; af.u[1] = hfB[kb];
        const short8 b4 = q0;
        q0 = q1; q1 = q2;
        if (kb < 13) q2 = *(const short8*)(w4q + (kb + 3) * 2560);
        #pragma unroll
        for (int f = 0; f < 4; ++f)
          acc[f] = __builtin_amdgcn_mfma_f32_32x32x16_bf16(af.v, wf[cur][f], acc[f], 0, 0, 0);
        acc[4] = __builtin_amdgcn_mfma_f32_32x32x16_bf16(af.v, b4, acc[4], 0, 0, 0);
      }
    }
    // b==0: h is zero, hs half contributes nothing -> skipped entirely.

    // ---- epilogue ----
    // C layout: col = lane&31, row = (r&3) + 8*(r>>2) + 4*(lane>>5).
    // Stage-batched shuffle trees (16 parallel chains).
    f32x16 gv, mx, Sv, Pv;
    #pragma unroll
    for (int r = 0; r < 16; ++r) gv[r] = acc[4][r] + c0b;  // cols>=16: exactly 0
    #pragma unroll
    for (int r = 0; r < 16; ++r) mx[r] = gv[r];
    #pragma unroll
    for (int r = 0; r < 16; ++r) { float t = __shfl_xor(mx[r], 1); mx[r] = fmaxf(mx[r], t); }
    #pragma unroll
    for (int r = 0; r < 16; ++r) { float t = __shfl_xor(mx[r], 2); mx[r] = fmaxf(mx[r], t); }
    #pragma unroll
    for (int r = 0; r < 16; ++r) { float t = __shfl_xor(mx[r], 4); mx[r] = fmaxf(mx[r], t); }
    #pragma unroll
    for (int r = 0; r < 16; ++r) gv[r] = __expf(gv[r] - mx[r]);   // gv := ex
    const bool pin = (lane & 7) <= s;
    #pragma unroll
    for (int r = 0; r < 16; ++r) { Sv[r] = gv[r]; Pv[r] = pin ? gv[r] : 0.f; }
    #pragma unroll
    for (int r = 0; r < 16; ++r) { Sv[r] += __shfl_xor(Sv[r], 1); Pv[r] += __shfl_xor(Pv[r], 1); }
    #pragma unroll
    for (int r = 0; r < 16; ++r) { Sv[r] += __shfl_xor(Sv[r], 2); Pv[r] += __shfl_xor(Pv[r], 2); }
    #pragma unroll
    for (int r = 0; r < 16; ++r) { Sv[r] += __shfl_xor(Sv[r], 4); Pv[r] += __shfl_xor(Pv[r], 4); }
    #pragma unroll
    for (int r = 0; r < 16; ++r) Pv[r] = __fdividef(Pv[r], Sv[r]);  // Pv := ratio
    f32x16 cinv, cfgv;
    #pragma unroll
    for (int r = 0; r < 16; ++r) cinv[r] = 1.f - __shfl(Pv[r], khalf * 32);
    #pragma unroll
    for (int r = 0; r < 16; ++r) cfgv[r] = __shfl(Pv[r], khalf * 32 + 8);

    #pragma unroll
    for (int r = 0; r < 16; ++r) {
      const int row = (r & 3) + 8 * (r >> 2) + 4 * khalf;
      const float cin = cinv[r];
      const float cfg = cfgv[r];
      const float og = sigmoidf_(acc[0][r] + bg[0]);
      const float cg = tanh_   (acc[1][r] + bg[1]);
      const float ig = sigmoidf_(acc[2][r] + bg[2]);
      const float fg = sigmoidf_(acc[3][r] + bg[3]);
      const float ov = cfg * cin;
      const float f2 = fg * ov + (cfg - ov);
      const float i2 = ig * ov + (cin - ov);
      const float cy = f2 * creg[r] + i2 * cg;
      creg[r] = cy;
      const float hy = og * tanh_(cy);
      if (!lastb) Ht[w][row][col] = f2bs(hy);   // wave-private transpose tile
      const int t = rb * 128 + w * 32 + row;
      if (t < len_s) {
        const size_t o = (size_t)(base_s + t) * (2 * H_) + (size_t)d * H_ + e;
        if (isf) ((float*)out)[o] = hy;
        else     ((bf16*)out)[o]  = __float2bfloat16(hy);
      }
    }

    // ---- hy -> A-frag image via coherent 8B atomic stores (4/lane);
    // skipped on the last step (never read). ----
    if (!lastb) {
      const int m  = lane & 31;
      const int k8 = lane >> 5;
      short* hbase = hs + (((size_t)((b & 1) * 2 + d) * NRB + rb) * 16 * NMB + w) * 512;
      #pragma unroll
      for (int c = 0; c < 2; ++c) {
        ull lo = *(const ull*)&Ht[w][m][c * 16 + k8 * 8];
        ull hi = *(const ull*)&Ht[w][m][c * 16 + k8 * 8 + 4];
        ull* q = (ull*)(hbase + (size_t)(2 * s + c) * NMB * 512) + lane * 2;
        __hip_atomic_store(q,     lo, __ATOMIC_RELAXED, __HIP_MEMORY_SCOPE_AGENT);
        __hip_atomic_store(q + 1, hi, __ATOMIC_RELAXED, __HIP_MEMORY_SCOPE_AGENT);
      }
    }

    // ---- arrive: barrier drains all stores (vmcnt(0) before s_barrier),
    // then one RELAXED add signals (proven write side). ----
    __syncthreads();
    if (tid == 0)
      __hip_atomic_fetch_add(gctr, 1, __ATOMIC_RELAXED, __HIP_MEMORY_SCOPE_AGENT);
  }

  if (b_hi < B_) {                 // per-step fallback mode: spill c carry
    #pragma unroll
    for (int r = 0; r < 16; ++r) csP[r * 64] = creg[r];
  }
}

// ---------------------------------------------------------------------------
extern "C" void kernel_launch(void* const* d_in, const int* in_sizes, int n_in,
                              void* d_out, int out_size, void* d_ws, size_t ws_size,
                              hipStream_t stream)
{
  const void* x    = d_in[0];
  const int*  sl   = (const int*)d_in[1];
  const void* W_ih = d_in[2];
  const void* b_ih = d_in[3];
  const void* W_hh = d_in[4];
  const void* b_hh = d_in[5];

  char* ws = (char*)d_ws;
  size_t off = 0;
  auto alloc = [&](size_t bytes) {
    void* p = ws + off;
    off = (off + bytes + 255) & ~(size_t)255;
    return p;
  };
  int*   meta = (int*)  alloc(128 * sizeof(int));
  short* xs   = (short*)alloc((size_t)B_ * T_ * D_ * sizeof(short));            // 32 MB
  short* Wsw  = (short*)alloc((size_t)2 * NSL * NKB * NF * 512 * sizeof(short)); // 2.6 MB
  short* hs   = (short*)alloc((size_t)2 * 2 * T_ * H_ * sizeof(short));         // 4 MB [parity][dir]
  float* bsum = (float*)alloc((size_t)G_ * sizeof(float));
  int*   ctr  = (int*)  alloc((size_t)32 * CTRSTRIDE * sizeof(int));            // padded: 1 line/group
  float* cs   = (float*)alloc((size_t)2 * NSL * NRB * NMB * 1024 * sizeof(float)); // 4 MB (fallback only)
  const bool have_cs = (off <= ws_size);

  // hs memset deleted (dead: step 0 writes parity 0 before step 1 reads it).
  hipMemsetAsync(ctr, 0, (size_t)32 * CTRSTRIDE * sizeof(int), stream);

  // ONE fused prep dispatch: meta+bsum, tiled xs (both-sides coalesced), Wsw.
  prep_all<<<1 + NBXT + NBWSW, 256, 0, stream>>>(
      x, sl, W_ih, b_ih, W_hh, b_hh, meta, bsum, (bf16*)xs, (bf16*)Wsw);

  // Preferred: cooperative persistent launch (co-residency guaranteed).
  int b_lo = 0, b_hi = B_;
  void* args[] = {(void*)&xs, (void*)&Wsw, (void*)&hs, (void*)&cs, (void*)&bsum,
                  (void*)&d_out, (void*)&meta, (void*)&ctr, (void*)&b_lo, (void*)&b_hi};
  hipError_t ce = hipLaunchCooperativeKernel((const void*)onlstm_persist,
                                             dim3(256), dim3(256), args, 0, stream);
  if (ce != hipSuccess) {
    (void)hipGetLastError();   // clear error state
    if (have_cs) {
      // Fallback: per-step launches; inter-step sync = kernel boundary.
      // Counter accumulates 8/group/launch, matching the 8*b thresholds.
      for (int b = 0; b < B_; ++b)
        onlstm_persist<<<dim3(256), dim3(256), 0, stream>>>(
            xs, Wsw, hs, cs, bsum, d_out, meta, ctr, b, b + 1);
    } else {
      // Last resort: regular persistent launch (structural residency + timeout).
      onlstm_persist<<<dim3(256), dim3(256), 0, stream>>>(
          xs, Wsw, hs, cs, bsum, d_out, meta, ctr, 0, B_);
    }
  }
}